// Round 1
// baseline (774.041 us; speedup 1.0000x reference)
//
#include <hip/hip_runtime.h>
#include <math.h>

#define T_ 1024
#define D_ 3
#define H_ 64

typedef _Float16 f16x8 __attribute__((ext_vector_type(8)));
typedef float f32x4 __attribute__((ext_vector_type(4)));

__device__ __forceinline__ float sigmoid_f(float x) {
    return __builtin_amdgcn_rcpf(1.0f + __expf(-x));
}

#define MFMA(A, B, C) __builtin_amdgcn_mfma_f32_16x16x32_f16((A), (B), (C), 0, 0, 0)

// Round-4: two independent 16-row sequence groups per block (grid 256, 1 block/CU).
// Each wave interleaves two recurrence chains -> one barrier serves two chain-steps,
// 8 independent gate-element dependency chains hide exp2/rcp + LDS latency in-wave.
// Math identical to round-3 (exp2-folded weights, shared-rcp sigmoid pair).
__global__ __launch_bounds__(256, 1) void gru_mfma6(
    const float* __restrict__ x1, const float* __restrict__ x2,
    const float* __restrict__ W_ih, const float* __restrict__ W_hh,
    const float* __restrict__ b_ih, const float* __restrict__ b_hh,
    const float* __restrict__ W1, const float* __restrict__ b1,
    const float* __restrict__ W2, const float* __restrict__ b2,
    float* __restrict__ out)
{
    const int lane = threadIdx.x & 63;
    const int w    = threadIdx.x >> 6;   // wave 0..3: owns units 16w..16w+15
    const int c    = lane & 15;          // A-m / C-D col / B-n
    const int q    = lane >> 4;          // quad
    const int u    = 16 * w + c;         // this lane's hidden-unit column
    const int seqA = blockIdx.x * 16;    // group A: seqs seqA..seqA+7
    const int seqB = seqA + 8;           // group B: seqs seqA+8..seqA+15

    const float SRZ = -1.44269504f;      // -log2(e): r,z rows (exp2(-x) form)
    const float SN  =  2.88539008f;      // 2*log2(e): n rows (exp2(2x) form)
    const float gsc[3] = {SRZ, SRZ, SN};

    // ---- h-part B-fragments (scaled): wf[g][ks][j] = s_g*W_hh[g*64+u][32ks+8q+j]
    f16x8 wf[3][2];
    #pragma unroll
    for (int g = 0; g < 3; ++g)
        #pragma unroll
        for (int ks = 0; ks < 2; ++ks) {
            const float* p = W_hh + (size_t)(g * 64 + u) * H_ + 32 * ks + q * 8;
            f16x8 v;
            #pragma unroll
            for (int j = 0; j < 8; ++j) v[j] = (_Float16)(p[j] * gsc[g]);
            wf[g][ks] = v;
        }

    // ---- x-part B-fragments (scaled; nonzero only in q==0 lanes, j<3) ----
    f16x8 bxf[3];
    #pragma unroll
    for (int g = 0; g < 3; ++g) {
        f16x8 v = {};
        if (q == 0) {
            #pragma unroll
            for (int d = 0; d < 3; ++d)
                v[d] = (_Float16)(W_ih[(size_t)(g * 64 + u) * D_ + d] * gsc[g]);
        }
        bxf[g] = v;
    }

    // ---- bias C-splats (scaled) ----
    const float comb_r = (b_ih[u]      + b_hh[u])      * SRZ;
    const float comb_z = (b_ih[64 + u] + b_hh[64 + u]) * SRZ;
    const float bxn    = b_ih[128 + u] * SN;
    const float bhn    = b_hh[128 + u] * SN;
    const f32x4 Cr  = {comb_r, comb_r, comb_r, comb_r};
    const f32x4 Cz  = {comb_z, comb_z, comb_z, comb_z};
    const f32x4 Cxn = {bxn, bxn, bxn, bxn};
    const f32x4 Chn = {bhn, bhn, bhn, bhn};

    // ---- x pointers: rows 0..7 = chain1 (x1), rows 8..15 = chain2 (x2) ----
    const float* xpA = (c < 8) ? (x1 + (size_t)(seqA + c) * (T_ * D_))
                               : (x2 + (size_t)(seqA + c - 8) * (T_ * D_));
    const float* xpB = (c < 8) ? (x1 + (size_t)(seqB + c) * (T_ * D_))
                               : (x2 + (size_t)(seqB + c - 8) * (T_ * D_));

    // h-tile double buffers per group: [row][unit], stride 72 halves
    __shared__ alignas(16) _Float16 hbA[2][16 * 72];
    __shared__ alignas(16) _Float16 hbB[2][16 * 72];
    __shared__ float dlds[16][68];

    float hA[4], hB[4];                  // rows 4q+0..3, col u, per group
    #pragma unroll
    for (int r = 0; r < 4; ++r) { hA[r] = 0.f; hB[r] = 0.f; }

    auto step = [&](int buf, float a0, float a1v, float a2v,
                             float b0, float b1v, float b2v) {
        // publish h(t) for both groups first — barrier wait ends sooner
        #pragma unroll
        for (int r = 0; r < 4; ++r) {
            hbA[buf][(4 * q + r) * 72 + u] = (_Float16)hA[r];
            hbB[buf][(4 * q + r) * 72 + u] = (_Float16)hB[r];
        }
        // x-part MFMAs: independent of h(t), fill the pre-barrier gap.
        f16x8 axA = {};
        axA[0] = (_Float16)a0; axA[1] = (_Float16)a1v; axA[2] = (_Float16)a2v;
        f16x8 axB = {};
        axB[0] = (_Float16)b0; axB[1] = (_Float16)b1v; axB[2] = (_Float16)b2v;
        f32x4 arA  = MFMA(axA, bxf[0], Cr);
        f32x4 azA  = MFMA(axA, bxf[1], Cz);
        f32x4 axnA = MFMA(axA, bxf[2], Cxn);
        f32x4 arB  = MFMA(axB, bxf[0], Cr);
        f32x4 azB  = MFMA(axB, bxf[1], Cz);
        f32x4 axnB = MFMA(axB, bxf[2], Cxn);
        __syncthreads();
        const f16x8 aA0 = *(const f16x8*)&hbA[buf][c * 72 + q * 8];        // k 0..31
        const f16x8 aA1 = *(const f16x8*)&hbA[buf][c * 72 + 32 + q * 8];   // k 32..63
        const f16x8 aB0 = *(const f16x8*)&hbB[buf][c * 72 + q * 8];
        const f16x8 aB1 = *(const f16x8*)&hbB[buf][c * 72 + 32 + q * 8];

        arA  = MFMA(aA0, wf[0][0], arA);
        azA  = MFMA(aA0, wf[1][0], azA);
        f32x4 ahnA = MFMA(aA0, wf[2][0], Chn);
        arA  = MFMA(aA1, wf[0][1], arA);
        azA  = MFMA(aA1, wf[1][1], azA);
        ahnA = MFMA(aA1, wf[2][1], ahnA);

        arB  = MFMA(aB0, wf[0][0], arB);
        azB  = MFMA(aB0, wf[1][0], azB);
        f32x4 ahnB = MFMA(aB0, wf[2][0], Chn);
        arB  = MFMA(aB1, wf[0][1], arB);
        azB  = MFMA(aB1, wf[1][1], azB);
        ahnB = MFMA(aB1, wf[2][1], ahnB);

        // gates A (overlaps B's matrix-pipe drain), then gates B
        #pragma unroll
        for (int r = 0; r < 4; ++r) {
            const float eu = __builtin_amdgcn_exp2f(arA[r]);
            const float ev = __builtin_amdgcn_exp2f(azA[r]);
            const float pu = 1.0f + eu, pv = 1.0f + ev;
            const float inv = __builtin_amdgcn_rcpf(pu * pv);
            const float rr = pv * inv;
            const float zz = pu * inv;
            const float tt = axnA[r] + rr * ahnA[r];
            const float e2 = __builtin_amdgcn_exp2f(tt);
            const float nn = 1.0f - 2.0f * __builtin_amdgcn_rcpf(e2 + 1.0f);
            hA[r] = nn + zz * (hA[r] - nn);
        }
        #pragma unroll
        for (int r = 0; r < 4; ++r) {
            const float eu = __builtin_amdgcn_exp2f(arB[r]);
            const float ev = __builtin_amdgcn_exp2f(azB[r]);
            const float pu = 1.0f + eu, pv = 1.0f + ev;
            const float inv = __builtin_amdgcn_rcpf(pu * pv);
            const float rr = pv * inv;
            const float zz = pu * inv;
            const float tt = axnB[r] + rr * ahnB[r];
            const float e2 = __builtin_amdgcn_exp2f(tt);
            const float nn = 1.0f - 2.0f * __builtin_amdgcn_rcpf(e2 + 1.0f);
            hB[r] = nn + zz * (hB[r] - nn);
        }
    };

    // x batched: float4 x3 = 12 floats = 4 steps; prefetch distance 4 steps
    const float4* x4A = (const float4*)xpA;
    const float4* x4B = (const float4*)xpB;
    float4 cA[3], cB[3];
    #pragma unroll
    for (int i = 0; i < 3; ++i) { cA[i] = x4A[i]; cB[i] = x4B[i]; }

    for (int t = 0; t < T_; t += 4) {
        float4 nA[3], nB[3];
        const int tb = (t + 4 < T_) ? (3 * (t + 4)) / 4 : (3 * t) / 4;
        #pragma unroll
        for (int i = 0; i < 3; ++i) { nA[i] = x4A[tb + i]; nB[i] = x4B[tb + i]; }
        step(0, cA[0].x, cA[0].y, cA[0].z,  cB[0].x, cB[0].y, cB[0].z);
        step(1, cA[0].w, cA[1].x, cA[1].y,  cB[0].w, cB[1].x, cB[1].y);
        step(0, cA[1].z, cA[1].w, cA[2].x,  cB[1].z, cB[1].w, cB[2].x);
        step(1, cA[2].y, cA[2].z, cA[2].w,  cB[2].y, cB[2].z, cB[2].w);
        #pragma unroll
        for (int i = 0; i < 3; ++i) { cA[i] = nA[i]; cB[i] = nB[i]; }
    }

    // ---- epilogue: |h1-h2| -> Linear(64,32)+ReLU -> Linear(32,1)+sigmoid ----
    #pragma unroll
    for (int r = 0; r < 4; ++r) {
        const float oA = __shfl_xor(hA[r], 32);    // row m <-> m^8 (q ^= 2)
        const float oB = __shfl_xor(hB[r], 32);
        if (q < 2) {
            dlds[4 * q + r][u]     = fabsf(hA[r] - oA);
            dlds[8 + 4 * q + r][u] = fabsf(hB[r] - oB);
        }
    }
    __syncthreads();
    if (w < 2) {                       // wave 0 -> group A, wave 1 -> group B
        const int s = lane >> 3;       // seq within group 0..7
        const int b = lane & 7;        // hidden-row group base
        const float* dl = &dlds[8 * w + s][0];
        float am[4];
        #pragma unroll
        for (int i = 0; i < 4; ++i) am[i] = b1[b + 8 * i];
        #pragma unroll
        for (int k4 = 0; k4 < 16; ++k4) {
            const float4 dvec = *(const float4*)&dl[k4 * 4];
            #pragma unroll
            for (int i = 0; i < 4; ++i) {
                const float4 wv = *(const float4*)&W1[(b + 8 * i) * H_ + k4 * 4];
                am[i] += dvec.x * wv.x + dvec.y * wv.y + dvec.z * wv.z + dvec.w * wv.w;
            }
        }
        float part = 0.f;
        #pragma unroll
        for (int i = 0; i < 4; ++i) part += fmaxf(am[i], 0.f) * W2[b + 8 * i];
        part += __shfl_xor(part, 1);
        part += __shfl_xor(part, 2);
        part += __shfl_xor(part, 4);
        if (b == 0) out[(w == 0 ? seqA : seqB) + s] = sigmoid_f(part + b2[0]);
    }
}

extern "C" void kernel_launch(void* const* d_in, const int* in_sizes, int n_in,
                              void* d_out, int out_size, void* d_ws, size_t ws_size,
                              hipStream_t stream) {
    const float* x1   = (const float*)d_in[0];
    const float* x2   = (const float*)d_in[1];
    const float* W_ih = (const float*)d_in[2];
    const float* W_hh = (const float*)d_in[3];
    const float* b_ih = (const float*)d_in[4];
    const float* b_hh = (const float*)d_in[5];
    const float* W1   = (const float*)d_in[6];
    const float* b1   = (const float*)d_in[7];
    const float* W2   = (const float*)d_in[8];
    const float* b2   = (const float*)d_in[9];

    const int B = in_sizes[0] / (T_ * D_);      // 4096
    dim3 grid(B / 16), block(256);
    gru_mfma6<<<grid, block, 0, stream>>>(x1, x2, W_ih, W_hh, b_ih, b_hh,
                                          W1, b1, W2, b2, (float*)d_out);
}

// Round 2
// 596.683 us; speedup vs baseline: 1.2972x; 1.2972x over previous
//
#include <hip/hip_runtime.h>
#include <math.h>

#define T_ 1024
#define D_ 3
#define H_ 64

typedef _Float16 f16x8 __attribute__((ext_vector_type(8)));
typedef float f32x4 __attribute__((ext_vector_type(4)));

__device__ __forceinline__ float sigmoid_f(float x) {
    return __builtin_amdgcn_rcpf(1.0f + __expf(-x));
}

#define MFMA(A, B, C) __builtin_amdgcn_mfma_f32_16x16x32_f16((A), (B), (C), 0, 0, 0)

// Round-5: round-3 structure (2 blocks/CU, 4 waves, one 16-row group) with
// latency-exposure fixes:
//  (1) raw `lgkmcnt(0); s_barrier` instead of __syncthreads -> vmcnt NOT
//      drained at the per-step barrier, so the 4-step x-prefetch actually
//      floats across barriers instead of being force-drained every 4 steps.
//  (2) x-MFMAs moved after the post-barrier ds_read issue: they cover the
//      ~120cy LDS read latency instead of idling pre-barrier.
//  (3) one-shot ~640cy phase stagger for blocks >=256 (co-resident pair on a
//      CU is {b, b+256}) so the two blocks' barrier/LDS stalls anti-phase.
__global__ __launch_bounds__(256, 2) void gru_mfma7(
    const float* __restrict__ x1, const float* __restrict__ x2,
    const float* __restrict__ W_ih, const float* __restrict__ W_hh,
    const float* __restrict__ b_ih, const float* __restrict__ b_hh,
    const float* __restrict__ W1, const float* __restrict__ b1,
    const float* __restrict__ W2, const float* __restrict__ b2,
    float* __restrict__ out)
{
    const int lane = threadIdx.x & 63;
    const int w    = threadIdx.x >> 6;   // wave 0..3: owns units 16w..16w+15
    const int c    = lane & 15;          // A-m / C-D col / B-n
    const int q    = lane >> 4;          // quad
    const int u    = 16 * w + c;         // this lane's hidden-unit column
    const int seq0 = blockIdx.x * 8;

    const float SRZ = -1.44269504f;      // -log2(e): r,z rows (exp2(-x) form)
    const float SN  =  2.88539008f;      // 2*log2(e): n rows (exp2(2x) form)
    const float gsc[3] = {SRZ, SRZ, SN};

    // ---- h-part B-fragments (scaled): wf[g][ks][j] = s_g*W_hh[g*64+u][32ks+8q+j]
    f16x8 wf[3][2];
    #pragma unroll
    for (int g = 0; g < 3; ++g)
        #pragma unroll
        for (int ks = 0; ks < 2; ++ks) {
            const float* p = W_hh + (size_t)(g * 64 + u) * H_ + 32 * ks + q * 8;
            f16x8 v;
            #pragma unroll
            for (int j = 0; j < 8; ++j) v[j] = (_Float16)(p[j] * gsc[g]);
            wf[g][ks] = v;
        }

    // ---- x-part B-fragments (scaled; nonzero only in q==0 lanes, j<3) ----
    f16x8 bxf[3];
    #pragma unroll
    for (int g = 0; g < 3; ++g) {
        f16x8 v = {};
        if (q == 0) {
            #pragma unroll
            for (int d = 0; d < 3; ++d)
                v[d] = (_Float16)(W_ih[(size_t)(g * 64 + u) * D_ + d] * gsc[g]);
        }
        bxf[g] = v;
    }

    // ---- bias C-splats (scaled) ----
    const float comb_r = (b_ih[u]      + b_hh[u])      * SRZ;
    const float comb_z = (b_ih[64 + u] + b_hh[64 + u]) * SRZ;
    const float bxn    = b_ih[128 + u] * SN;
    const float bhn    = b_hh[128 + u] * SN;
    const f32x4 Cr  = {comb_r, comb_r, comb_r, comb_r};
    const f32x4 Cz  = {comb_z, comb_z, comb_z, comb_z};
    const f32x4 Cxn = {bxn, bxn, bxn, bxn};
    const f32x4 Chn = {bhn, bhn, bhn, bhn};

    // ---- x pointer for A-frag row c (rows 0..7 = chain1, 8..15 = chain2) ----
    const float* xptr = (c < 8) ? (x1 + (size_t)(seq0 + c) * (T_ * D_))
                                : (x2 + (size_t)(seq0 + c - 8) * (T_ * D_));

    // h-tile double buffer: [row][unit], stride 72 halves
    __shared__ alignas(16) _Float16 hb[2][16 * 72];
    __shared__ float dlds[8][68];

    float h[4];                          // rows 4q+0..3, col u
    #pragma unroll
    for (int r = 0; r < 4; ++r) h[r] = 0.f;

    auto step = [&](int buf, float x0, float x1v, float x2v) {
        // publish h(t); LDS-visibility barrier only (vmcnt floats across)
        #pragma unroll
        for (int r = 0; r < 4; ++r)
            hb[buf][(4 * q + r) * 72 + u] = (_Float16)h[r];
        f16x8 ax = {};
        ax[0] = (_Float16)x0; ax[1] = (_Float16)x1v; ax[2] = (_Float16)x2v;
        asm volatile("s_waitcnt lgkmcnt(0)\n\ts_barrier" ::: "memory");
        // issue fragment reads immediately; x-MFMAs cover the LDS latency
        const f16x8 a0 = *(const f16x8*)&hb[buf][c * 72 + q * 8];        // k 0..31
        const f16x8 a1 = *(const f16x8*)&hb[buf][c * 72 + 32 + q * 8];   // k 32..63
        f32x4 ar  = MFMA(ax, bxf[0], Cr);
        f32x4 az  = MFMA(ax, bxf[1], Cz);
        f32x4 axn = MFMA(ax, bxf[2], Cxn);

        ar  = MFMA(a0, wf[0][0], ar);
        az  = MFMA(a0, wf[1][0], az);
        f32x4 ahn = MFMA(a0, wf[2][0], Chn);
        ar  = MFMA(a1, wf[0][1], ar);
        az  = MFMA(a1, wf[1][1], az);
        ahn = MFMA(a1, wf[2][1], ahn);

        // gates: ar,az hold -log2e*preact; axn,ahn hold 2log2e*parts
        #pragma unroll
        for (int r = 0; r < 4; ++r) {
            const float eu = __builtin_amdgcn_exp2f(ar[r]);   // e^{-pre_r}
            const float ev = __builtin_amdgcn_exp2f(az[r]);   // e^{-pre_z}
            const float pu = 1.0f + eu, pv = 1.0f + ev;
            const float inv = __builtin_amdgcn_rcpf(pu * pv);
            const float rr = pv * inv;                        // sigmoid(pre_r)
            const float zz = pu * inv;                        // sigmoid(pre_z)
            const float tt = axn[r] + rr * ahn[r];            // 2log2e * pre_n
            const float e2 = __builtin_amdgcn_exp2f(tt);      // e^{2 pre_n}
            const float nn = 1.0f - 2.0f * __builtin_amdgcn_rcpf(e2 + 1.0f);
            h[r] = nn + zz * (h[r] - nn);
        }
    };

    // one-shot anti-phase stagger: co-resident pair on a CU = {b, b+256}
    if (blockIdx.x & 256) __builtin_amdgcn_s_sleep(10);   // ~640 cycles

    // x batched: float4 x3 = 12 floats = 4 steps; prefetch distance 4 steps
    const float4* xp4 = (const float4*)xptr;
    float4 xc[3];
    #pragma unroll
    for (int i = 0; i < 3; ++i) xc[i] = xp4[i];

    for (int t = 0; t < T_; t += 4) {
        float4 xn[3];
        const int tb = (t + 4 < T_) ? (3 * (t + 4)) / 4 : (3 * t) / 4;
        #pragma unroll
        for (int i = 0; i < 3; ++i) xn[i] = xp4[tb + i];
        step(0, xc[0].x, xc[0].y, xc[0].z);
        step(1, xc[0].w, xc[1].x, xc[1].y);
        step(0, xc[1].z, xc[1].w, xc[2].x);
        step(1, xc[2].y, xc[2].z, xc[2].w);
        #pragma unroll
        for (int i = 0; i < 3; ++i) xc[i] = xn[i];
    }

    // ---- epilogue: |h1-h2| -> Linear(64,32)+ReLU -> Linear(32,1)+sigmoid ----
    #pragma unroll
    for (int r = 0; r < 4; ++r) {
        const float o = __shfl_xor(h[r], 32);     // row m <-> m^8 (q ^= 2)
        if (q < 2) dlds[4 * q + r][u] = fabsf(h[r] - o);
    }
    __syncthreads();
    if (w == 0) {
        const int s = lane >> 3;   // seq within block 0..7
        const int b = lane & 7;    // hidden-row group base
        float am[4];
        #pragma unroll
        for (int i = 0; i < 4; ++i) am[i] = b1[b + 8 * i];
        #pragma unroll
        for (int k4 = 0; k4 < 16; ++k4) {
            const float4 dvec = *(const float4*)&dlds[s][k4 * 4];
            #pragma unroll
            for (int i = 0; i < 4; ++i) {
                const float4 wv = *(const float4*)&W1[(b + 8 * i) * H_ + k4 * 4];
                am[i] += dvec.x * wv.x + dvec.y * wv.y + dvec.z * wv.z + dvec.w * wv.w;
            }
        }
        float part = 0.f;
        #pragma unroll
        for (int i = 0; i < 4; ++i) part += fmaxf(am[i], 0.f) * W2[b + 8 * i];
        part += __shfl_xor(part, 1);
        part += __shfl_xor(part, 2);
        part += __shfl_xor(part, 4);
        if (b == 0) out[seq0 + s] = sigmoid_f(part + b2[0]);
    }
}

extern "C" void kernel_launch(void* const* d_in, const int* in_sizes, int n_in,
                              void* d_out, int out_size, void* d_ws, size_t ws_size,
                              hipStream_t stream) {
    const float* x1   = (const float*)d_in[0];
    const float* x2   = (const float*)d_in[1];
    const float* W_ih = (const float*)d_in[2];
    const float* W_hh = (const float*)d_in[3];
    const float* b_ih = (const float*)d_in[4];
    const float* b_hh = (const float*)d_in[5];
    const float* W1   = (const float*)d_in[6];
    const float* b1   = (const float*)d_in[7];
    const float* W2   = (const float*)d_in[8];
    const float* b2   = (const float*)d_in[9];

    const int B = in_sizes[0] / (T_ * D_);      // 4096
    dim3 grid(B / 8), block(256);
    gru_mfma7<<<grid, block, 0, stream>>>(x1, x2, W_ih, W_hh, b_ih, b_hh,
                                          W1, b1, W2, b2, (float*)d_out);
}